// Round 1
// baseline (2401.694 us; speedup 1.0000x reference)
//
#include <hip/hip_runtime.h>
#include <math.h>

#define D_ 256
#define NL_ 4
#define NC_ 2
#define L_LEN 1024
#define NSTATE_ 64
#define DIN_ 512
#define H_ 8
#define P_ 64
#define CONVDIM_ 640
#define DPROJ_ 1160
#define EPS_ 1e-5f

__device__ __forceinline__ float siluf(float x) { return x / (1.f + expf(-x)); }
__device__ __forceinline__ float geluf(float x) { return 0.5f * x * (1.f + erff(x * 0.70710678118654752f)); }

// x[b,l,d] = emb[ids[b,l], d] + pos[l, d]
__global__ void k_embed(const int* __restrict__ ids, const float* __restrict__ emb,
                        const float* __restrict__ pos, float* __restrict__ x, int total) {
    int i = blockIdx.x * blockDim.x + threadIdx.x;
    if (i >= total) return;
    int d = i & (D_ - 1);
    int bl = i >> 8;            // D_=256
    int l = bl & (L_LEN - 1);
    x[i] = emb[ids[bl] * D_ + d] + pos[l * D_ + d];
}

// C[M,N] (+)= A[M,K] * B[N,K]^T ; M % 64 == 0, K % 16 == 0, N guarded.
template <bool ADD>
__global__ void gemm_nt(const float* __restrict__ A, const float* __restrict__ B,
                        float* __restrict__ C, int M, int N, int K) {
    __shared__ float As[16][64];
    __shared__ float Bs[16][64 + 1];
    int tm = threadIdx.x / 16;  // 0..15
    int tn = threadIdx.x % 16;  // 0..15
    int row0 = blockIdx.y * 64;
    int col0 = blockIdx.x * 64;
    int lm = threadIdx.x % 64;
    int lk = (threadIdx.x / 64) * 4;
    float acc[4][4] = {};
    for (int k0 = 0; k0 < K; k0 += 16) {
#pragma unroll
        for (int j = 0; j < 4; ++j)
            As[lk + j][lm] = A[(size_t)(row0 + lm) * K + k0 + lk + j];
        int nb = col0 + lm;
#pragma unroll
        for (int j = 0; j < 4; ++j)
            Bs[lk + j][lm] = (nb < N) ? B[(size_t)nb * K + k0 + lk + j] : 0.f;
        __syncthreads();
#pragma unroll
        for (int kk = 0; kk < 16; ++kk) {
            float a[4], b[4];
#pragma unroll
            for (int i = 0; i < 4; ++i) a[i] = As[kk][tm * 4 + i];
#pragma unroll
            for (int i = 0; i < 4; ++i) b[i] = Bs[kk][tn * 4 + i];
#pragma unroll
            for (int i = 0; i < 4; ++i)
#pragma unroll
                for (int j = 0; j < 4; ++j) acc[i][j] += a[i] * b[j];
        }
        __syncthreads();
    }
#pragma unroll
    for (int i = 0; i < 4; ++i) {
        int r = row0 + tm * 4 + i;
#pragma unroll
        for (int j = 0; j < 4; ++j) {
            int c = col0 + tn * 4 + j;
            if (c < N) {
                float v = acc[i][j];
                if (ADD) v += C[(size_t)r * N + c];
                C[(size_t)r * N + c] = v;
            }
        }
    }
}

// depthwise causal conv (k=4) over zx cols [512,1152) + bias + silu -> xBC[b,l,c]
__global__ void k_conv(const float* __restrict__ zx, const float* __restrict__ cw,
                       const float* __restrict__ cb, float* __restrict__ xBC, int total) {
    int i = blockIdx.x * blockDim.x + threadIdx.x;
    if (i >= total) return;
    int c = i % CONVDIM_;
    int bl = i / CONVDIM_;
    int l = bl & (L_LEN - 1);
    const float* src = zx + (size_t)bl * DPROJ_ + DIN_ + c;
    float acc = cb[c];
#pragma unroll
    for (int k = 0; k < 4; ++k) {
        int t = l - 3 + k;
        if (t >= 0) acc += cw[c * 4 + k] * src[(long)(k - 3) * DPROJ_];
    }
    xBC[i] = siluf(acc);
}

// dt = softplus(zx[...,-8:] + dtb); dA = exp(dt * -exp(A_log))
__global__ void k_dt(const float* __restrict__ zx, const float* __restrict__ dtbias,
                     const float* __restrict__ Alog, float* __restrict__ dt,
                     float* __restrict__ dA, int total) {
    int i = blockIdx.x * blockDim.x + threadIdx.x;
    if (i >= total) return;
    int h = i & (H_ - 1);
    int bl = i >> 3;
    float xv = zx[(size_t)bl * DPROJ_ + (DPROJ_ - H_) + h] + dtbias[h];
    float sp = fmaxf(xv, 0.f) + log1pf(expf(-fabsf(xv)));
    dt[i] = sp;
    dA[i] = expf(sp * (-expf(Alog[h])));
}

// SSM scan: one wave per (b,h,p), lane = n state index.
__global__ void k_scan(const float* __restrict__ xBC, const float* __restrict__ dt,
                       const float* __restrict__ dA, const float* __restrict__ Dp,
                       float* __restrict__ y) {
    int wid = (blockIdx.x * blockDim.x + threadIdx.x) >> 6;
    int lane = threadIdx.x & 63;
    int b = wid >> 9;  // 512 waves per batch
    int hp = wid & 511;
    int h = hp >> 6, p = hp & 63;
    float Dh = Dp[h];
    float hn = 0.f;
    const float* xb = xBC + (size_t)b * L_LEN * CONVDIM_;
    const float* dtb = dt + (size_t)b * L_LEN * H_ + h;
    const float* dab = dA + (size_t)b * L_LEN * H_ + h;
    float* yb = y + (size_t)b * L_LEN * DIN_ + h * P_ + p;
    for (int t = 0; t < L_LEN; ++t) {
        const float* row = xb + (size_t)t * CONVDIM_;
        float dtv = dtb[t * H_];
        float dAv = dab[t * H_];
        float xv = row[h * P_ + p];
        float Bn = row[DIN_ + lane];
        float Cn = row[DIN_ + NSTATE_ + lane];
        hn = dAv * hn + (dtv * xv) * Bn;
        float acc = hn * Cn;
#pragma unroll
        for (int o = 32; o; o >>= 1) acc += __shfl_xor(acc, o, 64);
        if (lane == 0) yb[(size_t)t * DIN_] = acc + Dh * xv;
    }
}

// y = rmsnorm(y * silu(z)) * norm_w   (in place, per (b,l) row)
__global__ void k_gatenorm(const float* __restrict__ zx, const float* __restrict__ nw,
                           float* __restrict__ y) {
    __shared__ float sred[4];
    int bl = blockIdx.x;
    float* yr = y + (size_t)bl * DIN_;
    const float* zr = zx + (size_t)bl * DPROJ_;
    int t = threadIdx.x;
    float g0 = yr[t] * siluf(zr[t]);
    float g1 = yr[t + 256] * siluf(zr[t + 256]);
    float ss = g0 * g0 + g1 * g1;
#pragma unroll
    for (int o = 32; o; o >>= 1) ss += __shfl_xor(ss, o, 64);
    if ((t & 63) == 0) sred[t >> 6] = ss;
    __syncthreads();
    ss = sred[0] + sred[1] + sred[2] + sred[3];
    float scale = rsqrtf(ss * (1.f / DIN_) + EPS_);
    yr[t] = g0 * scale * nw[t];
    yr[t + 256] = g1 * scale * nw[t + 256];
}

// pooled[b,d] = (mean_l + max_l) * 0.5
__global__ void k_pool(const float* __restrict__ x, float* __restrict__ pooled) {
    int b = blockIdx.x, d = threadIdx.x;
    const float* xb = x + (size_t)b * L_LEN * D_ + d;
    float s = 0.f, m = -INFINITY;
    for (int l = 0; l < L_LEN; ++l) {
        float v = xb[(size_t)l * D_];
        s += v;
        m = fmaxf(m, v);
    }
    pooled[b * D_ + d] = (s * (1.f / L_LEN) + m) * 0.5f;
}

// pooler -> gelu -> cls1 -> gelu -> cls2 ; one block per batch row
__global__ void k_head(const float* __restrict__ pooled, const float* __restrict__ pw,
                       const float* __restrict__ pb, const float* __restrict__ c1w,
                       const float* __restrict__ c1b, const float* __restrict__ c2w,
                       const float* __restrict__ c2b, float* __restrict__ out) {
    __shared__ float sp[256], s1[256], s2[128];
    int b = blockIdx.x, t = threadIdx.x;
    sp[t] = pooled[b * D_ + t];
    __syncthreads();
    float acc = pb[t];
    for (int d = 0; d < 256; ++d) acc += sp[d] * pw[t * 256 + d];
    s1[t] = geluf(acc);
    __syncthreads();
    if (t < 128) {
        float a = c1b[t];
        for (int d = 0; d < 256; ++d) a += s1[d] * c1w[t * 256 + d];
        s2[t] = geluf(a);
    }
    __syncthreads();
    if (t < 2) {
        float a = c2b[t];
        for (int d = 0; d < 128; ++d) a += s2[d] * c2w[t * 128 + d];
        out[b * NC_ + t] = a;
    }
}

extern "C" void kernel_launch(void* const* d_in, const int* in_sizes, int n_in,
                              void* d_out, int out_size, void* d_ws, size_t ws_size,
                              hipStream_t stream) {
    const int* ids    = (const int*)d_in[0];
    const float* emb  = (const float*)d_in[1];
    const float* pos  = (const float*)d_in[2];
    const float* Wins = (const float*)d_in[3];
    const float* cw   = (const float*)d_in[4];
    const float* cb   = (const float*)d_in[5];
    const float* dtb  = (const float*)d_in[6];
    const float* Alog = (const float*)d_in[7];
    const float* Dpar = (const float*)d_in[8];
    const float* nw   = (const float*)d_in[9];
    const float* Wout = (const float*)d_in[10];
    const float* pw   = (const float*)d_in[11];
    const float* pb   = (const float*)d_in[12];
    const float* c1w  = (const float*)d_in[13];
    const float* c1b  = (const float*)d_in[14];
    const float* c2w  = (const float*)d_in[15];
    const float* c2b  = (const float*)d_in[16];
    float* out = (float*)d_out;

    float* ws = (float*)d_ws;
    float* x      = ws;                 // 2*1024*256      = 524288
    float* zx     = x + 524288;         // 2*1024*1160     = 2375680
    float* xBC    = zx + 2375680;       // 2*1024*640      = 1310720
    float* dtbuf  = xBC + 1310720;      // 2*1024*8        = 16384
    float* dAbuf  = dtbuf + 16384;      // 16384
    float* y      = dAbuf + 16384;      // 2*1024*512      = 1048576
    float* pooled = y + 1048576;        // 512

    k_embed<<<2048, 256, 0, stream>>>(ids, emb, pos, x, 524288);
    for (int i = 0; i < NL_; ++i) {
        gemm_nt<false><<<dim3(19, 32), 256, 0, stream>>>(
            x, Wins + (size_t)i * DPROJ_ * D_, zx, 2048, DPROJ_, D_);
        k_conv<<<5120, 256, 0, stream>>>(
            zx, cw + (size_t)i * CONVDIM_ * 4, cb + (size_t)i * CONVDIM_, xBC, 1310720);
        k_dt<<<64, 256, 0, stream>>>(
            zx, dtb + i * H_, Alog + i * H_, dtbuf, dAbuf, 16384);
        k_scan<<<256, 256, 0, stream>>>(xBC, dtbuf, dAbuf, Dpar + i * H_, y);
        k_gatenorm<<<2048, 256, 0, stream>>>(zx, nw + (size_t)i * DIN_, y);
        gemm_nt<true><<<dim3(4, 32), 256, 0, stream>>>(
            y, Wout + (size_t)i * D_ * DIN_, x, 2048, D_, DIN_);
    }
    k_pool<<<2, 256, 0, stream>>>(x, pooled);
    k_head<<<2, 256, 0, stream>>>(pooled, pw, pb, c1w, c1b, c2w, c2b, out);
}

// Round 2
// 730.899 us; speedup vs baseline: 3.2859x; 3.2859x over previous
//
#include <hip/hip_runtime.h>
#include <math.h>

#define D_ 256
#define NL_ 4
#define NC_ 2
#define L_LEN 1024
#define NSTATE_ 64
#define DIN_ 512
#define H_ 8
#define P_ 64
#define CONVDIM_ 640
#define DPROJ_ 1160
#define EPS_ 1e-5f
#define Q_ 64
#define NCH_ 16   // L_LEN / Q_

__device__ __forceinline__ float siluf(float x) { return x / (1.f + expf(-x)); }
__device__ __forceinline__ float geluf(float x) { return 0.5f * x * (1.f + erff(x * 0.70710678118654752f)); }

// x[b,l,d] = emb[ids[b,l], d] + pos[l, d]
__global__ void k_embed(const int* __restrict__ ids, const float* __restrict__ emb,
                        const float* __restrict__ pos, float* __restrict__ x, int total) {
    int i = blockIdx.x * blockDim.x + threadIdx.x;
    if (i >= total) return;
    int d = i & (D_ - 1);
    int bl = i >> 8;
    int l = bl & (L_LEN - 1);
    x[i] = emb[ids[bl] * D_ + d] + pos[l * D_ + d];
}

// C[M,N] (+)= A[M,K] * B[N,K]^T ; M % 64 == 0, K % 16 == 0, N guarded.
template <bool ADD>
__global__ void gemm_nt(const float* __restrict__ A, const float* __restrict__ B,
                        float* __restrict__ C, int M, int N, int K) {
    __shared__ float As[16][64];
    __shared__ float Bs[16][64 + 1];
    int tm = threadIdx.x / 16;
    int tn = threadIdx.x % 16;
    int row0 = blockIdx.y * 64;
    int col0 = blockIdx.x * 64;
    int lm = threadIdx.x % 64;
    int lk = (threadIdx.x / 64) * 4;
    float acc[4][4] = {};
    for (int k0 = 0; k0 < K; k0 += 16) {
#pragma unroll
        for (int j = 0; j < 4; ++j)
            As[lk + j][lm] = A[(size_t)(row0 + lm) * K + k0 + lk + j];
        int nb = col0 + lm;
#pragma unroll
        for (int j = 0; j < 4; ++j)
            Bs[lk + j][lm] = (nb < N) ? B[(size_t)nb * K + k0 + lk + j] : 0.f;
        __syncthreads();
#pragma unroll
        for (int kk = 0; kk < 16; ++kk) {
            float a[4], b[4];
#pragma unroll
            for (int i = 0; i < 4; ++i) a[i] = As[kk][tm * 4 + i];
#pragma unroll
            for (int i = 0; i < 4; ++i) b[i] = Bs[kk][tn * 4 + i];
#pragma unroll
            for (int i = 0; i < 4; ++i)
#pragma unroll
                for (int j = 0; j < 4; ++j) acc[i][j] += a[i] * b[j];
        }
        __syncthreads();
    }
#pragma unroll
    for (int i = 0; i < 4; ++i) {
        int r = row0 + tm * 4 + i;
#pragma unroll
        for (int j = 0; j < 4; ++j) {
            int c = col0 + tn * 4 + j;
            if (c < N) {
                float v = acc[i][j];
                if (ADD) v += C[(size_t)r * N + c];
                C[(size_t)r * N + c] = v;
            }
        }
    }
}

// depthwise causal conv (k=4) + bias + silu
__global__ void k_conv(const float* __restrict__ zx, const float* __restrict__ cw,
                       const float* __restrict__ cb, float* __restrict__ xBC, int total) {
    int i = blockIdx.x * blockDim.x + threadIdx.x;
    if (i >= total) return;
    int c = i % CONVDIM_;
    int bl = i / CONVDIM_;
    int l = bl & (L_LEN - 1);
    const float* src = zx + (size_t)bl * DPROJ_ + DIN_ + c;
    float acc = cb[c];
#pragma unroll
    for (int k = 0; k < 4; ++k) {
        int t = l - 3 + k;
        if (t >= 0) acc += cw[c * 4 + k] * src[(long)(k - 3) * DPROJ_];
    }
    xBC[i] = siluf(acc);
}

// dt = softplus(raw + dtb); ldA = dt * (-exp(A_log))   [log of dA]
__global__ void k_dt(const float* __restrict__ zx, const float* __restrict__ dtbias,
                     const float* __restrict__ Alog, float* __restrict__ dt,
                     float* __restrict__ ldA, int total) {
    int i = blockIdx.x * blockDim.x + threadIdx.x;
    if (i >= total) return;
    int h = i & (H_ - 1);
    int bl = i >> 3;
    float xv = zx[(size_t)bl * DPROJ_ + (DPROJ_ - H_) + h] + dtbias[h];
    float sp = fmaxf(xv, 0.f) + log1pf(expf(-fabsf(xv)));
    dt[i] = sp;
    ldA[i] = sp * (-expf(Alog[h]));
}

// Per-chunk local end-state: Sbuf[bh,c,p,n] = sum_j exp(cs[63]-cs[j])*dt_j*x_j[p]*B_j[n]
__global__ void __launch_bounds__(256) k_chunk_fwd(const float* __restrict__ xBC,
        const float* __restrict__ dt, const float* __restrict__ ldA,
        float* __restrict__ Sbuf, float* __restrict__ decay) {
    __shared__ float xs[64][65];
    __shared__ float Bs[64][65];
    __shared__ float sdt[64], sld[64], cs[64], wj[64];
    int c = blockIdx.x, bh = blockIdx.y;
    int b = bh >> 3, h = bh & 7;
    int l0 = c << 6;
    int tid = threadIdx.x, wid = tid >> 6, lane = tid & 63;
    for (int r = 0; r < 64; r += 4) {
        int j = r + wid;
        const float* row = xBC + (size_t)(b * L_LEN + l0 + j) * CONVDIM_;
        xs[j][lane] = row[h * P_ + lane];
        Bs[j][lane] = row[DIN_ + lane];
    }
    if (tid < 64) {
        size_t idx = (size_t)(b * L_LEN + l0 + tid) * H_ + h;
        sdt[tid] = dt[idx];
        sld[tid] = ldA[idx];
    }
    __syncthreads();
    if (tid == 0) {
        float s = 0.f;
        for (int j = 0; j < 64; ++j) { s += sld[j]; cs[j] = s; }
    }
    __syncthreads();
    if (tid < 64) wj[tid] = expf(cs[63] - cs[tid]) * sdt[tid];
    if (tid == 0) decay[bh * NCH_ + c] = expf(cs[63]);
    __syncthreads();
    int p = lane, ng = wid << 4;
    float acc[16] = {};
    for (int j = 0; j < 64; ++j) {
        float wx = wj[j] * xs[j][p];
#pragma unroll
        for (int nn = 0; nn < 16; ++nn) acc[nn] += wx * Bs[j][ng + nn];
    }
    float* dst = Sbuf + ((size_t)(bh * NCH_ + c) * P_ + p) * NSTATE_ + ng;
#pragma unroll
    for (int nn = 0; nn < 16; ++nn) dst[nn] = acc[nn];
}

// In-place cross-chunk scan: Sbuf[c] becomes the INCOMING state for chunk c.
__global__ void k_chunk_scan(float* __restrict__ Sbuf, const float* __restrict__ decay) {
    int bh = blockIdx.x, tid = threadIdx.x;
    float run[16] = {};
    for (int c = 0; c < NCH_; ++c) {
        float* ptr = Sbuf + (size_t)(bh * NCH_ + c) * 4096 + tid * 16;
        float dec = decay[bh * NCH_ + c];
        float tmp[16];
#pragma unroll
        for (int k = 0; k < 16; ++k) tmp[k] = ptr[k];
#pragma unroll
        for (int k = 0; k < 16; ++k) ptr[k] = run[k];
#pragma unroll
        for (int k = 0; k < 16; ++k) run[k] = dec * run[k] + tmp[k];
    }
}

// Y[i,p] = e^{cs[i]} * C_i·S_in[p]  +  sum_{j<=i} e^{cs[i]-cs[j]} dt_j (B_j·C_i) x_j[p]  + D_h x_i[p]
__global__ void __launch_bounds__(256) k_chunk_out(const float* __restrict__ xBC,
        const float* __restrict__ dt, const float* __restrict__ ldA,
        const float* __restrict__ Sbuf, const float* __restrict__ Dp,
        float* __restrict__ y) {
    __shared__ float Ab[64][65];   // holds B, then S_in, then x
    __shared__ float Cs[64][65];
    __shared__ float Gs[64][65];
    __shared__ float sdt[64], sld[64], cs[64];
    int c = blockIdx.x, bh = blockIdx.y;
    int b = bh >> 3, h = bh & 7;
    int l0 = c << 6;
    int tid = threadIdx.x, wid = tid >> 6, lane = tid & 63;
    for (int r = 0; r < 64; r += 4) {
        int j = r + wid;
        const float* row = xBC + (size_t)(b * L_LEN + l0 + j) * CONVDIM_;
        Ab[j][lane] = row[DIN_ + lane];            // B
        Cs[j][lane] = row[DIN_ + NSTATE_ + lane];  // C
    }
    if (tid < 64) {
        size_t idx = (size_t)(b * L_LEN + l0 + tid) * H_ + h;
        sdt[tid] = dt[idx];
        sld[tid] = ldA[idx];
    }
    __syncthreads();
    if (tid == 0) {
        float s = 0.f;
        for (int j = 0; j < 64; ++j) { s += sld[j]; cs[j] = s; }
    }
    __syncthreads();
    int i = lane, jg = wid << 4;
    // G[i][j] = B_j · C_i
    {
        float g[16] = {};
        for (int n = 0; n < 64; ++n) {
            float cv = Cs[i][n];
#pragma unroll
            for (int jj = 0; jj < 16; ++jj) g[jj] += cv * Ab[jg + jj][n];
        }
#pragma unroll
        for (int jj = 0; jj < 16; ++jj) Gs[i][jg + jj] = g[jj];
    }
    __syncthreads();
    // stage S_in into Ab[p][n]
    {
        const float* src = Sbuf + (size_t)(bh * NCH_ + c) * 4096;
        for (int r = 0; r < 64; r += 4) {
            int pp = r + wid;
            Ab[pp][lane] = src[pp * 64 + lane];
        }
    }
    __syncthreads();
    int pg = jg;
    float acc[16] = {};
    // inter-chunk: e^{cs[i]} * sum_n C_i[n] * S_in[p][n]
    {
        for (int n = 0; n < 64; ++n) {
            float cv = Cs[i][n];
#pragma unroll
            for (int pp = 0; pp < 16; ++pp) acc[pp] += cv * Ab[pg + pp][n];
        }
        float ei = expf(cs[i]);
#pragma unroll
        for (int pp = 0; pp < 16; ++pp) acc[pp] *= ei;
    }
    __syncthreads();
    // stage x into Ab[j][p]
    for (int r = 0; r < 64; r += 4) {
        int j = r + wid;
        Ab[j][lane] = xBC[(size_t)(b * L_LEN + l0 + j) * CONVDIM_ + h * P_ + lane];
    }
    __syncthreads();
    float csi = cs[i];
    for (int j = 0; j < 64; ++j) {
        float w = (j <= i) ? expf(fminf(csi - cs[j], 0.f)) * (sdt[j] * Gs[i][j]) : 0.f;
#pragma unroll
        for (int pp = 0; pp < 16; ++pp) acc[pp] += w * Ab[j][pg + pp];
    }
    float Dh = Dp[h];
    float* dst = y + (size_t)(b * L_LEN + l0 + i) * DIN_ + h * P_ + pg;
#pragma unroll
    for (int pp = 0; pp < 16; ++pp) dst[pp] = acc[pp] + Dh * Ab[i][pg + pp];
}

// y = rmsnorm(y * silu(z)) * norm_w
__global__ void k_gatenorm(const float* __restrict__ zx, const float* __restrict__ nw,
                           float* __restrict__ y) {
    __shared__ float sred[4];
    int bl = blockIdx.x;
    float* yr = y + (size_t)bl * DIN_;
    const float* zr = zx + (size_t)bl * DPROJ_;
    int t = threadIdx.x;
    float g0 = yr[t] * siluf(zr[t]);
    float g1 = yr[t + 256] * siluf(zr[t + 256]);
    float ss = g0 * g0 + g1 * g1;
#pragma unroll
    for (int o = 32; o; o >>= 1) ss += __shfl_xor(ss, o, 64);
    if ((t & 63) == 0) sred[t >> 6] = ss;
    __syncthreads();
    ss = sred[0] + sred[1] + sred[2] + sred[3];
    float scale = rsqrtf(ss * (1.f / DIN_) + EPS_);
    yr[t] = g0 * scale * nw[t];
    yr[t + 256] = g1 * scale * nw[t + 256];
}

__global__ void k_pool(const float* __restrict__ x, float* __restrict__ pooled) {
    int b = blockIdx.x, d = threadIdx.x;
    const float* xb = x + (size_t)b * L_LEN * D_ + d;
    float s = 0.f, m = -INFINITY;
    for (int l = 0; l < L_LEN; ++l) {
        float v = xb[(size_t)l * D_];
        s += v;
        m = fmaxf(m, v);
    }
    pooled[b * D_ + d] = (s * (1.f / L_LEN) + m) * 0.5f;
}

__global__ void k_head(const float* __restrict__ pooled, const float* __restrict__ pw,
                       const float* __restrict__ pb, const float* __restrict__ c1w,
                       const float* __restrict__ c1b, const float* __restrict__ c2w,
                       const float* __restrict__ c2b, float* __restrict__ out) {
    __shared__ float sp[256], s1[256], s2[128];
    int b = blockIdx.x, t = threadIdx.x;
    sp[t] = pooled[b * D_ + t];
    __syncthreads();
    float acc = pb[t];
    for (int d = 0; d < 256; ++d) acc += sp[d] * pw[t * 256 + d];
    s1[t] = geluf(acc);
    __syncthreads();
    if (t < 128) {
        float a = c1b[t];
        for (int d = 0; d < 256; ++d) a += s1[d] * c1w[t * 256 + d];
        s2[t] = geluf(a);
    }
    __syncthreads();
    if (t < 2) {
        float a = c2b[t];
        for (int d = 0; d < 128; ++d) a += s2[d] * c2w[t * 128 + d];
        out[b * NC_ + t] = a;
    }
}

extern "C" void kernel_launch(void* const* d_in, const int* in_sizes, int n_in,
                              void* d_out, int out_size, void* d_ws, size_t ws_size,
                              hipStream_t stream) {
    const int* ids    = (const int*)d_in[0];
    const float* emb  = (const float*)d_in[1];
    const float* pos  = (const float*)d_in[2];
    const float* Wins = (const float*)d_in[3];
    const float* cw   = (const float*)d_in[4];
    const float* cb   = (const float*)d_in[5];
    const float* dtb  = (const float*)d_in[6];
    const float* Alog = (const float*)d_in[7];
    const float* Dpar = (const float*)d_in[8];
    const float* nw   = (const float*)d_in[9];
    const float* Wout = (const float*)d_in[10];
    const float* pw   = (const float*)d_in[11];
    const float* pb   = (const float*)d_in[12];
    const float* c1w  = (const float*)d_in[13];
    const float* c1b  = (const float*)d_in[14];
    const float* c2w  = (const float*)d_in[15];
    const float* c2b  = (const float*)d_in[16];
    float* out = (float*)d_out;

    float* ws = (float*)d_ws;
    float* x      = ws;                 // 524288
    float* zx     = x + 524288;         // 2375680
    float* xBC    = zx + 2375680;       // 1310720
    float* dtbuf  = xBC + 1310720;      // 16384
    float* ldAbuf = dtbuf + 16384;      // 16384
    float* y      = ldAbuf + 16384;     // 1048576
    float* Sbuf   = y + 1048576;        // 2*8*16*64*64 = 1048576
    float* decay  = Sbuf + 1048576;     // 256
    float* pooled = decay + 256;        // 512

    k_embed<<<2048, 256, 0, stream>>>(ids, emb, pos, x, 524288);
    for (int i = 0; i < NL_; ++i) {
        gemm_nt<false><<<dim3(19, 32), 256, 0, stream>>>(
            x, Wins + (size_t)i * DPROJ_ * D_, zx, 2048, DPROJ_, D_);
        k_conv<<<5120, 256, 0, stream>>>(
            zx, cw + (size_t)i * CONVDIM_ * 4, cb + (size_t)i * CONVDIM_, xBC, 1310720);
        k_dt<<<64, 256, 0, stream>>>(
            zx, dtb + i * H_, Alog + i * H_, dtbuf, ldAbuf, 16384);
        k_chunk_fwd<<<dim3(NCH_, 16), 256, 0, stream>>>(xBC, dtbuf, ldAbuf, Sbuf, decay);
        k_chunk_scan<<<16, 256, 0, stream>>>(Sbuf, decay);
        k_chunk_out<<<dim3(NCH_, 16), 256, 0, stream>>>(xBC, dtbuf, ldAbuf, Sbuf,
                                                        Dpar + i * H_, y);
        k_gatenorm<<<2048, 256, 0, stream>>>(zx, nw + (size_t)i * DIN_, y);
        gemm_nt<true><<<dim3(4, 32), 256, 0, stream>>>(
            y, Wout + (size_t)i * D_ * DIN_, x, 2048, D_, DIN_);
    }
    k_pool<<<2, 256, 0, stream>>>(x, pooled);
    k_head<<<2, 256, 0, stream>>>(pooled, pw, pb, c1w, c1b, c2w, c2b, out);
}

// Round 3
// 628.854 us; speedup vs baseline: 3.8192x; 1.1623x over previous
//
#include <hip/hip_runtime.h>
#include <math.h>

#define D_ 256
#define NL_ 4
#define NC_ 2
#define L_LEN 1024
#define NSTATE_ 64
#define DIN_ 512
#define H_ 8
#define P_ 64
#define CONVDIM_ 640
#define DPROJ_ 1160
#define EPS_ 1e-5f
#define Q_ 64
#define NCH_ 16   // L_LEN / Q_

__device__ __forceinline__ float siluf(float x) { return x / (1.f + expf(-x)); }
__device__ __forceinline__ float geluf(float x) { return 0.5f * x * (1.f + erff(x * 0.70710678118654752f)); }

// x[b,l,d] = emb[ids[b,l], d] + pos[l, d]
__global__ void k_embed(const int* __restrict__ ids, const float* __restrict__ emb,
                        const float* __restrict__ pos, float* __restrict__ x, int total) {
    int i = blockIdx.x * blockDim.x + threadIdx.x;
    if (i >= total) return;
    int d = i & (D_ - 1);
    int bl = i >> 8;
    int l = bl & (L_LEN - 1);
    x[i] = emb[ids[bl] * D_ + d] + pos[l * D_ + d];
}

// C[M,N] (+)= A[M,K_total] * B[N,K_total]^T over k-range [blockIdx.z*kchunk, +kchunk)
// BM=128, BN=64, BK=16; 256 threads, 8x4 per thread; reg-prefetch of global tiles.
// ATOMIC: atomicAdd into C (split-K / fused residual-add). else plain store.
#define AS_(k, r) Asm[(k) * 132 + (r)]
#define BS_(k, r) Bsm[(k) * 68 + (r)]
template <bool ATOMIC>
__global__ void __launch_bounds__(256) gemm_f32t(const float* __restrict__ A,
        const float* __restrict__ B, float* __restrict__ C,
        int M, int N, int K, int kchunk) {
    __shared__ float Asm[16 * 132];
    __shared__ float Bsm[16 * 68];
    const int tid = threadIdx.x;
    const int row0 = blockIdx.y * 128;
    const int col0 = blockIdx.x * 64;
    const int kbase = blockIdx.z * kchunk;
    const int arow = tid >> 2;   // 0..63
    const int akq = tid & 3;     // 0..3 -> k offset akq*4
    const int brow = col0 + arow;
    const bool bok = brow < N;

    float4 pa0, pa1, pb0;
    {
        const float* a0 = &A[(size_t)(row0 + arow) * K + kbase + akq * 4];
        pa0 = *(const float4*)a0;
        pa1 = *(const float4*)(a0 + (size_t)64 * K);
        pb0 = bok ? *(const float4*)&B[(size_t)brow * K + kbase + akq * 4]
                  : float4{0.f, 0.f, 0.f, 0.f};
    }
    const int tm = tid >> 4;  // 0..15 -> rows tm*8
    const int tn = tid & 15;  // 0..15 -> cols tn*4
    float acc[8][4] = {};
    const int kend = kbase + kchunk;
    for (int k0 = kbase; k0 < kend; k0 += 16) {
        __syncthreads();
        AS_(akq * 4 + 0, arow) = pa0.x;
        AS_(akq * 4 + 1, arow) = pa0.y;
        AS_(akq * 4 + 2, arow) = pa0.z;
        AS_(akq * 4 + 3, arow) = pa0.w;
        AS_(akq * 4 + 0, arow + 64) = pa1.x;
        AS_(akq * 4 + 1, arow + 64) = pa1.y;
        AS_(akq * 4 + 2, arow + 64) = pa1.z;
        AS_(akq * 4 + 3, arow + 64) = pa1.w;
        BS_(akq * 4 + 0, arow) = pb0.x;
        BS_(akq * 4 + 1, arow) = pb0.y;
        BS_(akq * 4 + 2, arow) = pb0.z;
        BS_(akq * 4 + 3, arow) = pb0.w;
        __syncthreads();
        if (k0 + 16 < kend) {
            const float* a0 = &A[(size_t)(row0 + arow) * K + k0 + 16 + akq * 4];
            pa0 = *(const float4*)a0;
            pa1 = *(const float4*)(a0 + (size_t)64 * K);
            pb0 = bok ? *(const float4*)&B[(size_t)brow * K + k0 + 16 + akq * 4]
                      : float4{0.f, 0.f, 0.f, 0.f};
        }
#pragma unroll
        for (int kk = 0; kk < 16; ++kk) {
            float a[8], b[4];
#pragma unroll
            for (int i = 0; i < 8; ++i) a[i] = AS_(kk, tm * 8 + i);
#pragma unroll
            for (int j = 0; j < 4; ++j) b[j] = BS_(kk, tn * 4 + j);
#pragma unroll
            for (int i = 0; i < 8; ++i)
#pragma unroll
                for (int j = 0; j < 4; ++j) acc[i][j] += a[i] * b[j];
        }
    }
    int cbase = col0 + tn * 4;
#pragma unroll
    for (int i = 0; i < 8; ++i) {
        size_t r = (size_t)(row0 + tm * 8 + i) * N + cbase;
        if (ATOMIC) {
            if (cbase < N) {
#pragma unroll
                for (int j = 0; j < 4; ++j) atomicAdd(&C[r + j], acc[i][j]);
            }
        } else {
            if (cbase + 3 < N) {
                float4 v = {acc[i][0], acc[i][1], acc[i][2], acc[i][3]};
                *(float4*)&C[r] = v;
            } else {
#pragma unroll
                for (int j = 0; j < 4; ++j)
                    if (cbase + j < N) C[r + j] = acc[i][j];
            }
        }
    }
}

// depthwise causal conv (k=4) + bias + silu
__global__ void k_conv(const float* __restrict__ zx, const float* __restrict__ cw,
                       const float* __restrict__ cb, float* __restrict__ xBC, int total) {
    int i = blockIdx.x * blockDim.x + threadIdx.x;
    if (i >= total) return;
    int c = i % CONVDIM_;
    int bl = i / CONVDIM_;
    int l = bl & (L_LEN - 1);
    const float* src = zx + (size_t)bl * DPROJ_ + DIN_ + c;
    float acc = cb[c];
#pragma unroll
    for (int k = 0; k < 4; ++k) {
        int t = l - 3 + k;
        if (t >= 0) acc += cw[c * 4 + k] * src[(long)(k - 3) * DPROJ_];
    }
    xBC[i] = siluf(acc);
}

// dt = softplus(raw + dtb); ldA = dt * (-exp(A_log))
__global__ void k_dt(const float* __restrict__ zx, const float* __restrict__ dtbias,
                     const float* __restrict__ Alog, float* __restrict__ dt,
                     float* __restrict__ ldA, int total) {
    int i = blockIdx.x * blockDim.x + threadIdx.x;
    if (i >= total) return;
    int h = i & (H_ - 1);
    int bl = i >> 3;
    float xv = zx[(size_t)bl * DPROJ_ + (DPROJ_ - H_) + h] + dtbias[h];
    float sp = fmaxf(xv, 0.f) + log1pf(expf(-fabsf(xv)));
    dt[i] = sp;
    ldA[i] = sp * (-expf(Alog[h]));
}

// Per-chunk local end-state
__global__ void __launch_bounds__(256) k_chunk_fwd(const float* __restrict__ xBC,
        const float* __restrict__ dt, const float* __restrict__ ldA,
        float* __restrict__ Sbuf, float* __restrict__ decay) {
    __shared__ float xs[64][65];
    __shared__ float Bs[64][65];
    __shared__ float sdt[64], sld[64], cs[64], wj[64];
    int c = blockIdx.x, bh = blockIdx.y;
    int b = bh >> 3, h = bh & 7;
    int l0 = c << 6;
    int tid = threadIdx.x, wid = tid >> 6, lane = tid & 63;
    for (int r = 0; r < 64; r += 4) {
        int j = r + wid;
        const float* row = xBC + (size_t)(b * L_LEN + l0 + j) * CONVDIM_;
        xs[j][lane] = row[h * P_ + lane];
        Bs[j][lane] = row[DIN_ + lane];
    }
    if (tid < 64) {
        size_t idx = (size_t)(b * L_LEN + l0 + tid) * H_ + h;
        sdt[tid] = dt[idx];
        sld[tid] = ldA[idx];
    }
    __syncthreads();
    if (tid == 0) {
        float s = 0.f;
        for (int j = 0; j < 64; ++j) { s += sld[j]; cs[j] = s; }
    }
    __syncthreads();
    if (tid < 64) wj[tid] = expf(cs[63] - cs[tid]) * sdt[tid];
    if (tid == 0) decay[bh * NCH_ + c] = expf(cs[63]);
    __syncthreads();
    int p = lane, ng = wid << 4;
    float acc[16] = {};
    for (int j = 0; j < 64; ++j) {
        float wx = wj[j] * xs[j][p];
#pragma unroll
        for (int nn = 0; nn < 16; ++nn) acc[nn] += wx * Bs[j][ng + nn];
    }
    float* dst = Sbuf + ((size_t)(bh * NCH_ + c) * P_ + p) * NSTATE_ + ng;
#pragma unroll
    for (int nn = 0; nn < 16; ++nn) dst[nn] = acc[nn];
}

// In-place cross-chunk scan
__global__ void k_chunk_scan(float* __restrict__ Sbuf, const float* __restrict__ decay) {
    int bh = blockIdx.x, tid = threadIdx.x;
    float run[16] = {};
    for (int c = 0; c < NCH_; ++c) {
        float* ptr = Sbuf + (size_t)(bh * NCH_ + c) * 4096 + tid * 16;
        float dec = decay[bh * NCH_ + c];
        float tmp[16];
#pragma unroll
        for (int k = 0; k < 16; ++k) tmp[k] = ptr[k];
#pragma unroll
        for (int k = 0; k < 16; ++k) ptr[k] = run[k];
#pragma unroll
        for (int k = 0; k < 16; ++k) run[k] = dec * run[k] + tmp[k];
    }
}

// Per-chunk output
__global__ void __launch_bounds__(256) k_chunk_out(const float* __restrict__ xBC,
        const float* __restrict__ dt, const float* __restrict__ ldA,
        const float* __restrict__ Sbuf, const float* __restrict__ Dp,
        float* __restrict__ y) {
    __shared__ float Ab[64][65];
    __shared__ float Cs[64][65];
    __shared__ float Gs[64][65];
    __shared__ float sdt[64], sld[64], cs[64];
    int c = blockIdx.x, bh = blockIdx.y;
    int b = bh >> 3, h = bh & 7;
    int l0 = c << 6;
    int tid = threadIdx.x, wid = tid >> 6, lane = tid & 63;
    for (int r = 0; r < 64; r += 4) {
        int j = r + wid;
        const float* row = xBC + (size_t)(b * L_LEN + l0 + j) * CONVDIM_;
        Ab[j][lane] = row[DIN_ + lane];            // B
        Cs[j][lane] = row[DIN_ + NSTATE_ + lane];  // C
    }
    if (tid < 64) {
        size_t idx = (size_t)(b * L_LEN + l0 + tid) * H_ + h;
        sdt[tid] = dt[idx];
        sld[tid] = ldA[idx];
    }
    __syncthreads();
    if (tid == 0) {
        float s = 0.f;
        for (int j = 0; j < 64; ++j) { s += sld[j]; cs[j] = s; }
    }
    __syncthreads();
    int i = lane, jg = wid << 4;
    {
        float g[16] = {};
        for (int n = 0; n < 64; ++n) {
            float cv = Cs[i][n];
#pragma unroll
            for (int jj = 0; jj < 16; ++jj) g[jj] += cv * Ab[jg + jj][n];
        }
#pragma unroll
        for (int jj = 0; jj < 16; ++jj) Gs[i][jg + jj] = g[jj];
    }
    __syncthreads();
    {
        const float* src = Sbuf + (size_t)(bh * NCH_ + c) * 4096;
        for (int r = 0; r < 64; r += 4) {
            int pp = r + wid;
            Ab[pp][lane] = src[pp * 64 + lane];
        }
    }
    __syncthreads();
    int pg = jg;
    float acc[16] = {};
    {
        for (int n = 0; n < 64; ++n) {
            float cv = Cs[i][n];
#pragma unroll
            for (int pp = 0; pp < 16; ++pp) acc[pp] += cv * Ab[pg + pp][n];
        }
        float ei = expf(cs[i]);
#pragma unroll
        for (int pp = 0; pp < 16; ++pp) acc[pp] *= ei;
    }
    __syncthreads();
    for (int r = 0; r < 64; r += 4) {
        int j = r + wid;
        Ab[j][lane] = xBC[(size_t)(b * L_LEN + l0 + j) * CONVDIM_ + h * P_ + lane];
    }
    __syncthreads();
    float csi = cs[i];
    for (int j = 0; j < 64; ++j) {
        float w = (j <= i) ? expf(fminf(csi - cs[j], 0.f)) * (sdt[j] * Gs[i][j]) : 0.f;
#pragma unroll
        for (int pp = 0; pp < 16; ++pp) acc[pp] += w * Ab[j][pg + pp];
    }
    float Dh = Dp[h];
    float* dst = y + (size_t)(b * L_LEN + l0 + i) * DIN_ + h * P_ + pg;
#pragma unroll
    for (int pp = 0; pp < 16; ++pp) dst[pp] = acc[pp] + Dh * Ab[i][pg + pp];
}

// y = rmsnorm(y * silu(z)) * norm_w
__global__ void k_gatenorm(const float* __restrict__ zx, const float* __restrict__ nw,
                           float* __restrict__ y) {
    __shared__ float sred[4];
    int bl = blockIdx.x;
    float* yr = y + (size_t)bl * DIN_;
    const float* zr = zx + (size_t)bl * DPROJ_;
    int t = threadIdx.x;
    float g0 = yr[t] * siluf(zr[t]);
    float g1 = yr[t + 256] * siluf(zr[t + 256]);
    float ss = g0 * g0 + g1 * g1;
#pragma unroll
    for (int o = 32; o; o >>= 1) ss += __shfl_xor(ss, o, 64);
    if ((t & 63) == 0) sred[t >> 6] = ss;
    __syncthreads();
    ss = sred[0] + sred[1] + sred[2] + sred[3];
    float scale = rsqrtf(ss * (1.f / DIN_) + EPS_);
    yr[t] = g0 * scale * nw[t];
    yr[t + 256] = g1 * scale * nw[t + 256];
}

// two-stage pooling
__global__ void k_pool1(const float* __restrict__ x, float* __restrict__ psum,
                        float* __restrict__ pmax) {
    int b = blockIdx.y, ch = blockIdx.x, d = threadIdx.x;
    const float* xb = x + ((size_t)(b * L_LEN) + ch * 64) * D_ + d;
    float s = 0.f, m = -INFINITY;
    for (int l = 0; l < 64; ++l) {
        float v = xb[(size_t)l * D_];
        s += v;
        m = fmaxf(m, v);
    }
    psum[(b * 16 + ch) * D_ + d] = s;
    pmax[(b * 16 + ch) * D_ + d] = m;
}

__global__ void k_pool2(const float* __restrict__ psum, const float* __restrict__ pmax,
                        float* __restrict__ pooled) {
    int b = blockIdx.x, d = threadIdx.x;
    float s = 0.f, m = -INFINITY;
    for (int ch = 0; ch < 16; ++ch) {
        s += psum[(b * 16 + ch) * D_ + d];
        m = fmaxf(m, pmax[(b * 16 + ch) * D_ + d]);
    }
    pooled[b * D_ + d] = (s * (1.f / L_LEN) + m) * 0.5f;
}

__global__ void k_head(const float* __restrict__ pooled, const float* __restrict__ pw,
                       const float* __restrict__ pb, const float* __restrict__ c1w,
                       const float* __restrict__ c1b, const float* __restrict__ c2w,
                       const float* __restrict__ c2b, float* __restrict__ out) {
    __shared__ float sp[256], s1[256], s2[128];
    int b = blockIdx.x, t = threadIdx.x;
    sp[t] = pooled[b * D_ + t];
    __syncthreads();
    float acc = pb[t];
    for (int d = 0; d < 256; ++d) acc += sp[d] * pw[t * 256 + d];
    s1[t] = geluf(acc);
    __syncthreads();
    if (t < 128) {
        float a = c1b[t];
        for (int d = 0; d < 256; ++d) a += s1[d] * c1w[t * 256 + d];
        s2[t] = geluf(a);
    }
    __syncthreads();
    if (t < 2) {
        float a = c2b[t];
        for (int d = 0; d < 128; ++d) a += s2[d] * c2w[t * 128 + d];
        out[b * NC_ + t] = a;
    }
}

extern "C" void kernel_launch(void* const* d_in, const int* in_sizes, int n_in,
                              void* d_out, int out_size, void* d_ws, size_t ws_size,
                              hipStream_t stream) {
    const int* ids    = (const int*)d_in[0];
    const float* emb  = (const float*)d_in[1];
    const float* pos  = (const float*)d_in[2];
    const float* Wins = (const float*)d_in[3];
    const float* cw   = (const float*)d_in[4];
    const float* cb   = (const float*)d_in[5];
    const float* dtb  = (const float*)d_in[6];
    const float* Alog = (const float*)d_in[7];
    const float* Dpar = (const float*)d_in[8];
    const float* nw   = (const float*)d_in[9];
    const float* Wout = (const float*)d_in[10];
    const float* pw   = (const float*)d_in[11];
    const float* pb   = (const float*)d_in[12];
    const float* c1w  = (const float*)d_in[13];
    const float* c1b  = (const float*)d_in[14];
    const float* c2w  = (const float*)d_in[15];
    const float* c2b  = (const float*)d_in[16];
    float* out = (float*)d_out;

    float* ws = (float*)d_ws;
    float* x      = ws;                 // 524288
    float* zx     = x + 524288;         // 2375680
    float* xBC    = zx + 2375680;       // 1310720
    float* dtbuf  = xBC + 1310720;      // 16384
    float* ldAbuf = dtbuf + 16384;      // 16384
    float* y      = ldAbuf + 16384;     // 1048576
    float* Sbuf   = y + 1048576;        // 1048576
    float* decay  = Sbuf + 1048576;     // 256
    float* pooled = decay + 256;        // 512
    float* psum   = pooled + 512;       // 8192
    float* pmax   = psum + 8192;        // 8192

    k_embed<<<2048, 256, 0, stream>>>(ids, emb, pos, x, 524288);
    for (int i = 0; i < NL_; ++i) {
        gemm_f32t<false><<<dim3(19, 16, 1), 256, 0, stream>>>(
            x, Wins + (size_t)i * DPROJ_ * D_, zx, 2048, DPROJ_, D_, D_);
        k_conv<<<5120, 256, 0, stream>>>(
            zx, cw + (size_t)i * CONVDIM_ * 4, cb + (size_t)i * CONVDIM_, xBC, 1310720);
        k_dt<<<64, 256, 0, stream>>>(
            zx, dtb + i * H_, Alog + i * H_, dtbuf, ldAbuf, 16384);
        k_chunk_fwd<<<dim3(NCH_, 16), 256, 0, stream>>>(xBC, dtbuf, ldAbuf, Sbuf, decay);
        k_chunk_scan<<<16, 256, 0, stream>>>(Sbuf, decay);
        k_chunk_out<<<dim3(NCH_, 16), 256, 0, stream>>>(xBC, dtbuf, ldAbuf, Sbuf,
                                                        Dpar + i * H_, y);
        k_gatenorm<<<2048, 256, 0, stream>>>(zx, nw + (size_t)i * DIN_, y);
        gemm_f32t<true><<<dim3(4, 16, 4), 256, 0, stream>>>(
            y, Wout + (size_t)i * D_ * DIN_, x, 2048, D_, DIN_, 128);
    }
    k_pool1<<<dim3(16, 2), 256, 0, stream>>>(x, psum, pmax);
    k_pool2<<<2, 256, 0, stream>>>(psum, pmax, pooled);
    k_head<<<2, 256, 0, stream>>>(pooled, pw, pb, c1w, c1b, c2w, c2b, out);
}